// Round 1
// baseline (132.134 us; speedup 1.0000x reference)
//
#include <hip/hip_runtime.h>
#include <hip/hip_bf16.h>
#include <math.h>

#define NNODES 4096
#define FDIM 128
#define HDIM 3
#define BGRAPH 8
#define GAT_ALPHA 0.2f

// ---------------------------------------------------------------------------
// Kernel A: per-node Wh = emb[i,:]@W  (128x3), e_src[i], e_dst[i].
// One wave (64 lanes) per node row; each lane handles 2 features.
// Packs tbl[i] = (Wh0, Wh1, Wh2, e_dst) for single-float4 consumption later.
// ---------------------------------------------------------------------------
__global__ void wh_kernel(const float* __restrict__ emb, const float* __restrict__ W,
                          const float* __restrict__ a,
                          float4* __restrict__ tbl, float* __restrict__ esrc) {
    int i = blockIdx.x;
    int lane = threadIdx.x;  // 0..63
    const float2 ev = *reinterpret_cast<const float2*>(emb + (size_t)i * FDIM + lane * 2);
    int t0 = lane * 2;
    float wh0 = ev.x * W[t0 * 3 + 0] + ev.y * W[(t0 + 1) * 3 + 0];
    float wh1 = ev.x * W[t0 * 3 + 1] + ev.y * W[(t0 + 1) * 3 + 1];
    float wh2 = ev.x * W[t0 * 3 + 2] + ev.y * W[(t0 + 1) * 3 + 2];
    for (int off = 32; off >= 1; off >>= 1) {
        wh0 += __shfl_xor(wh0, off);
        wh1 += __shfl_xor(wh1, off);
        wh2 += __shfl_xor(wh2, off);
    }
    if (lane == 0) {
        float es = wh0 * a[0] + wh1 * a[1] + wh2 * a[2];
        float ed = wh0 * a[3] + wh1 * a[4] + wh2 * a[5];
        tbl[i] = make_float4(wh0, wh1, wh2, ed);
        esrc[i] = es;
    }
}

// ---------------------------------------------------------------------------
// Kernel A2: stats[0..2] = sum_j Wh[j,:]  (uniform-softmax fallback),
//            stats[3]    = max_j e_dst[j] (global shift base).
// ---------------------------------------------------------------------------
__global__ void stats_kernel(const float4* __restrict__ tbl, float* __restrict__ stats) {
    __shared__ float4 sh[256];
    int tid = threadIdx.x;
    float s0 = 0, s1 = 0, s2 = 0, mx = -INFINITY;
    for (int i = tid; i < NNODES; i += 256) {
        float4 v = tbl[i];
        s0 += v.x; s1 += v.y; s2 += v.z; mx = fmaxf(mx, v.w);
    }
    sh[tid] = make_float4(s0, s1, s2, mx);
    __syncthreads();
    for (int off = 128; off >= 1; off >>= 1) {
        if (tid < off) {
            float4 o = sh[tid + off];
            float4 m = sh[tid];
            m.x += o.x; m.y += o.y; m.z += o.z; m.w = fmaxf(m.w, o.w);
            sh[tid] = m;
        }
        __syncthreads();
    }
    if (tid == 0) {
        stats[0] = sh[0].x; stats[1] = sh[0].y; stats[2] = sh[0].z; stats[3] = sh[0].w;
    }
}

// ---------------------------------------------------------------------------
// Kernel B: the big one. For each row r=(b,i): online masked softmax + PV.
//   m_i = lrelu(e_src[i] + dmax) >= true row max  (lrelu is monotone), so
//   all weights exp(e - m_i) <= 1 and lanes accumulate PURE SUMS (no max merge).
// adj read as coalesced int4 (16B/lane). Table staged in 64KB LDS, swizzled
// j -> (j&3)*1024 + (j>>2) so ds_read_b128 is lane-consecutive (conflict-free).
// ---------------------------------------------------------------------------
__global__ __launch_bounds__(256) void attn_kernel(
    const int* __restrict__ adj, const float4* __restrict__ tbl,
    const float* __restrict__ esrc, const float* __restrict__ stats,
    float* __restrict__ hout) {
    __shared__ float4 ltbl[NNODES];  // 64 KB -> 2 blocks/CU
    int tid = threadIdx.x;
    for (int k = tid; k < NNODES; k += 256)
        ltbl[(k & 3) * 1024 + (k >> 2)] = tbl[k];
    __syncthreads();

    const float dmax = stats[3];
    const float L2E = 1.4426950408889634f;
    int wid = tid >> 6, lane = tid & 63;
    int gw = blockIdx.x * 4 + wid;
    int totalWaves = gridDim.x * 4;

    for (int r = gw; r < BGRAPH * NNODES; r += totalWaves) {
        int i = r & (NNODES - 1);
        float es = esrc[i];
        float m = es + dmax;
        m = fmaxf(m, GAT_ALPHA * m);      // lrelu(es + dmax) = row max bound
        float bias = -m * L2E;
        const int4* ap = reinterpret_cast<const int4*>(adj + (size_t)r * NNODES);

        float s = 0.f, a0 = 0.f, a1 = 0.f, a2 = 0.f;
        #pragma unroll 4
        for (int T = 0; T < 16; ++T) {
            int4 av = ap[T * 64 + lane];   // adj[j] for j = 4*(T*64+lane)+c
            int base = T * 64 + lane;
            {
                float4 tv = ltbl[0 * 1024 + base];
                float x = es + tv.w; x = fmaxf(x, GAT_ALPHA * x);
                float w = __builtin_amdgcn_exp2f(x * L2E + bias);
                w = (av.x > 0) ? w : 0.f;
                s += w; a0 += w * tv.x; a1 += w * tv.y; a2 += w * tv.z;
            }
            {
                float4 tv = ltbl[1 * 1024 + base];
                float x = es + tv.w; x = fmaxf(x, GAT_ALPHA * x);
                float w = __builtin_amdgcn_exp2f(x * L2E + bias);
                w = (av.y > 0) ? w : 0.f;
                s += w; a0 += w * tv.x; a1 += w * tv.y; a2 += w * tv.z;
            }
            {
                float4 tv = ltbl[2 * 1024 + base];
                float x = es + tv.w; x = fmaxf(x, GAT_ALPHA * x);
                float w = __builtin_amdgcn_exp2f(x * L2E + bias);
                w = (av.z > 0) ? w : 0.f;
                s += w; a0 += w * tv.x; a1 += w * tv.y; a2 += w * tv.z;
            }
            {
                float4 tv = ltbl[3 * 1024 + base];
                float x = es + tv.w; x = fmaxf(x, GAT_ALPHA * x);
                float w = __builtin_amdgcn_exp2f(x * L2E + bias);
                w = (av.w > 0) ? w : 0.f;
                s += w; a0 += w * tv.x; a1 += w * tv.y; a2 += w * tv.z;
            }
        }
        // cross-lane merge: pure sums thanks to precomputed shift
        for (int off = 32; off >= 1; off >>= 1) {
            s  += __shfl_xor(s, off);
            a0 += __shfl_xor(a0, off);
            a1 += __shfl_xor(a1, off);
            a2 += __shfl_xor(a2, off);
        }
        if (lane == 0) {
            float h0, h1, h2;
            if (s > 0.f) {
                h0 = a0 / s; h1 = a1 / s; h2 = a2 / s;
            } else {  // fully-masked row: reference softmax degenerates to uniform
                h0 = stats[0] * (1.f / NNODES);
                h1 = stats[1] * (1.f / NNODES);
                h2 = stats[2] * (1.f / NNODES);
            }
            h0 = h0 > 0.f ? h0 : expf(h0) - 1.f;   // elu
            h1 = h1 > 0.f ? h1 : expf(h1) - 1.f;
            h2 = h2 > 0.f ? h2 : expf(h2) - 1.f;
            float* hp = hout + (size_t)r * 3;
            hp[0] = h0; hp[1] = h1; hp[2] = h2;
        }
    }
}

// ---------------------------------------------------------------------------
// Kernel C: out[b,o] = elu_h[b,:] . fc1_w[o,:] + fc1_b[o].  800 blocks.
// ---------------------------------------------------------------------------
__global__ void fc_kernel(const float* __restrict__ h, const float* __restrict__ w,
                          const float* __restrict__ bias, float* __restrict__ out) {
    int bo = blockIdx.x;
    int bg = bo / 100, o = bo % 100;
    const float* hrow = h + (size_t)bg * (NNODES * HDIM);
    const float* wrow = w + (size_t)o * (NNODES * HDIM);
    int tid = threadIdx.x;
    float p = 0.f;
    for (int k = tid; k < NNODES * HDIM; k += 256) p += hrow[k] * wrow[k];
    __shared__ float sh[256];
    sh[tid] = p;
    __syncthreads();
    for (int off = 128; off >= 1; off >>= 1) {
        if (tid < off) sh[tid] += sh[tid + off];
        __syncthreads();
    }
    if (tid == 0) out[bo] = sh[0] + bias[o];
}

extern "C" void kernel_launch(void* const* d_in, const int* in_sizes, int n_in,
                              void* d_out, int out_size, void* d_ws, size_t ws_size,
                              hipStream_t stream) {
    const int*   adj  = (const int*)d_in[0];
    const float* emb  = (const float*)d_in[1];
    const float* W    = (const float*)d_in[2];
    const float* a    = (const float*)d_in[3];
    const float* fc1w = (const float*)d_in[4];
    const float* fc1b = (const float*)d_in[5];
    float* out = (float*)d_out;

    char* ws = (char*)d_ws;
    float4* tbl   = (float4*)ws;                       // 64 KB
    float*  esrc  = (float*)(ws + 65536);              // 16 KB
    float*  stats = (float*)(ws + 65536 + 16384);      // 16 B (padded to 256)
    float*  hout  = (float*)(ws + 65536 + 16384 + 256);// 8*4096*3*4 = 384 KB

    wh_kernel<<<NNODES, 64, 0, stream>>>(emb, W, a, tbl, esrc);
    stats_kernel<<<1, 256, 0, stream>>>(tbl, stats);
    attn_kernel<<<512, 256, 0, stream>>>(adj, tbl, esrc, stats, hout);
    fc_kernel<<<BGRAPH * 100, 256, 0, stream>>>(hout, fc1w, fc1b, out);
}

// Round 2
// 108.509 us; speedup vs baseline: 1.2177x; 1.2177x over previous
//
#include <hip/hip_runtime.h>
#include <hip/hip_bf16.h>
#include <math.h>

#define NNODES 4096
#define FDIM 128
#define HDIM 3
#define BGRAPH 8
#define GAT_ALPHA 0.2f

typedef int v4i __attribute__((ext_vector_type(4)));

// ---------------------------------------------------------------------------
// Kernel A: per-node Wh = emb[i,:]@W  (128x3), e_src[i], e_dst[i].
// One wave per node row, 4 waves/block. Packs tbl[i] = (Wh0,Wh1,Wh2,e_dst).
// ---------------------------------------------------------------------------
__global__ __launch_bounds__(256) void wh_kernel(
    const float* __restrict__ emb, const float* __restrict__ W,
    const float* __restrict__ a,
    float4* __restrict__ tbl, float* __restrict__ esrc) {
    int wid = threadIdx.x >> 6, lane = threadIdx.x & 63;
    int i = blockIdx.x * 4 + wid;
    const float2 ev = *reinterpret_cast<const float2*>(emb + (size_t)i * FDIM + lane * 2);
    int t0 = lane * 2;
    float wh0 = ev.x * W[t0 * 3 + 0] + ev.y * W[(t0 + 1) * 3 + 0];
    float wh1 = ev.x * W[t0 * 3 + 1] + ev.y * W[(t0 + 1) * 3 + 1];
    float wh2 = ev.x * W[t0 * 3 + 2] + ev.y * W[(t0 + 1) * 3 + 2];
    for (int off = 32; off >= 1; off >>= 1) {
        wh0 += __shfl_xor(wh0, off);
        wh1 += __shfl_xor(wh1, off);
        wh2 += __shfl_xor(wh2, off);
    }
    if (lane == 0) {
        float es = wh0 * a[0] + wh1 * a[1] + wh2 * a[2];
        float ed = wh0 * a[3] + wh1 * a[4] + wh2 * a[5];
        tbl[i] = make_float4(wh0, wh1, wh2, ed);
        esrc[i] = es;
    }
}

// ---------------------------------------------------------------------------
// Kernel B: masked softmax + PV, one wave per (b,i) row, 8 rows/wave.
//   Stage tbl into LDS swizzled j -> (j&3)*1024 + (j>>2) (conflict-free
//   ds_read_b128), and block-reduce {sum_j Wh, max_j e_dst} in the same pass
//   (replaces the old single-block stats kernel).
//   Shift m = lrelu(e_src[i] + dmax) >= true row max (lrelu monotone), so
//   lanes accumulate pure sums; cross-lane merge is 4 shuffle-sums.
// ---------------------------------------------------------------------------
__global__ __launch_bounds__(512, 4) void attn_kernel(
    const int* __restrict__ adj, const float4* __restrict__ tbl,
    const float* __restrict__ esrc, float* __restrict__ hout) {
    __shared__ float4 ltbl[NNODES];  // 64 KB -> 2 blocks/CU (LDS-limited)
    __shared__ float4 red[8];
    int tid = threadIdx.x;
    int wid = tid >> 6, lane = tid & 63;

    float s0 = 0.f, s1 = 0.f, s2 = 0.f, mx = -INFINITY;
    for (int k = tid; k < NNODES; k += 512) {
        float4 v = tbl[k];
        ltbl[(k & 3) * 1024 + (k >> 2)] = v;
        s0 += v.x; s1 += v.y; s2 += v.z; mx = fmaxf(mx, v.w);
    }
    for (int off = 32; off >= 1; off >>= 1) {
        s0 += __shfl_xor(s0, off);
        s1 += __shfl_xor(s1, off);
        s2 += __shfl_xor(s2, off);
        mx = fmaxf(mx, __shfl_xor(mx, off));
    }
    if (lane == 0) red[wid] = make_float4(s0, s1, s2, mx);
    __syncthreads();
    if (tid < 8) {
        float4 v = red[tid];
        for (int off = 4; off >= 1; off >>= 1) {
            v.x += __shfl_xor(v.x, off);
            v.y += __shfl_xor(v.y, off);
            v.z += __shfl_xor(v.z, off);
            v.w = fmaxf(v.w, __shfl_xor(v.w, off));
        }
        if (tid == 0) red[0] = v;
    }
    __syncthreads();
    const float4 st = red[0];   // (sum Wh0, sum Wh1, sum Wh2, dmax)
    const float dmax = st.w;
    const float L2E = 1.4426950408889634f;

    int gw = blockIdx.x * 8 + wid;           // 512 blocks * 8 waves = 4096 waves
    for (int r = gw; r < BGRAPH * NNODES; r += 4096) {  // 8 rows per wave
        int i = r & (NNODES - 1);
        float es = esrc[i];
        float m = es + dmax;
        m = fmaxf(m, GAT_ALPHA * m);         // lrelu(es + dmax) = row max bound
        float bias = -m * L2E;
        const v4i* ap = reinterpret_cast<const v4i*>(adj + (size_t)r * NNODES);

        float s = 0.f, a0 = 0.f, a1 = 0.f, a2 = 0.f;
        #pragma unroll 2
        for (int T = 0; T < 16; ++T) {
            v4i av = __builtin_nontemporal_load(ap + T * 64 + lane);
            int base = T * 64 + lane;
            {
                float4 tv = ltbl[0 * 1024 + base];
                float x = es + tv.w; x = fmaxf(x, GAT_ALPHA * x);
                float w = __builtin_amdgcn_exp2f(x * L2E + bias);
                w = (av.x > 0) ? w : 0.f;
                s += w; a0 += w * tv.x; a1 += w * tv.y; a2 += w * tv.z;
            }
            {
                float4 tv = ltbl[1 * 1024 + base];
                float x = es + tv.w; x = fmaxf(x, GAT_ALPHA * x);
                float w = __builtin_amdgcn_exp2f(x * L2E + bias);
                w = (av.y > 0) ? w : 0.f;
                s += w; a0 += w * tv.x; a1 += w * tv.y; a2 += w * tv.z;
            }
            {
                float4 tv = ltbl[2 * 1024 + base];
                float x = es + tv.w; x = fmaxf(x, GAT_ALPHA * x);
                float w = __builtin_amdgcn_exp2f(x * L2E + bias);
                w = (av.z > 0) ? w : 0.f;
                s += w; a0 += w * tv.x; a1 += w * tv.y; a2 += w * tv.z;
            }
            {
                float4 tv = ltbl[3 * 1024 + base];
                float x = es + tv.w; x = fmaxf(x, GAT_ALPHA * x);
                float w = __builtin_amdgcn_exp2f(x * L2E + bias);
                w = (av.w > 0) ? w : 0.f;
                s += w; a0 += w * tv.x; a1 += w * tv.y; a2 += w * tv.z;
            }
        }
        for (int off = 32; off >= 1; off >>= 1) {
            s  += __shfl_xor(s, off);
            a0 += __shfl_xor(a0, off);
            a1 += __shfl_xor(a1, off);
            a2 += __shfl_xor(a2, off);
        }
        if (lane == 0) {
            float h0, h1, h2;
            if (s > 0.f) {
                h0 = a0 / s; h1 = a1 / s; h2 = a2 / s;
            } else {  // fully-masked row: reference softmax degenerates to uniform
                h0 = st.x * (1.f / NNODES);
                h1 = st.y * (1.f / NNODES);
                h2 = st.z * (1.f / NNODES);
            }
            h0 = h0 > 0.f ? h0 : expf(h0) - 1.f;   // elu
            h1 = h1 > 0.f ? h1 : expf(h1) - 1.f;
            h2 = h2 > 0.f ? h2 : expf(h2) - 1.f;
            float* hp = hout + (size_t)r * 3;
            hp[0] = h0; hp[1] = h1; hp[2] = h2;
        }
    }
}

// ---------------------------------------------------------------------------
// Kernel C: out[b,o] = elu_h[b,:] . fc1_w[o,:] + fc1_b[o].  800 blocks.
// ---------------------------------------------------------------------------
__global__ void fc_kernel(const float* __restrict__ h, const float* __restrict__ w,
                          const float* __restrict__ bias, float* __restrict__ out) {
    int bo = blockIdx.x;
    int bg = bo / 100, o = bo % 100;
    const float* hrow = h + (size_t)bg * (NNODES * HDIM);
    const float* wrow = w + (size_t)o * (NNODES * HDIM);
    int tid = threadIdx.x;
    float p = 0.f;
    for (int k = tid; k < NNODES * HDIM; k += 256) p += hrow[k] * wrow[k];
    __shared__ float sh[256];
    sh[tid] = p;
    __syncthreads();
    for (int off = 128; off >= 1; off >>= 1) {
        if (tid < off) sh[tid] += sh[tid + off];
        __syncthreads();
    }
    if (tid == 0) out[bo] = sh[0] + bias[o];
}

extern "C" void kernel_launch(void* const* d_in, const int* in_sizes, int n_in,
                              void* d_out, int out_size, void* d_ws, size_t ws_size,
                              hipStream_t stream) {
    const int*   adj  = (const int*)d_in[0];
    const float* emb  = (const float*)d_in[1];
    const float* W    = (const float*)d_in[2];
    const float* a    = (const float*)d_in[3];
    const float* fc1w = (const float*)d_in[4];
    const float* fc1b = (const float*)d_in[5];
    float* out = (float*)d_out;

    char* ws = (char*)d_ws;
    float4* tbl  = (float4*)ws;                        // 64 KB
    float*  esrc = (float*)(ws + 65536);               // 16 KB
    float*  hout = (float*)(ws + 65536 + 16384);       // 8*4096*3*4 = 384 KB

    wh_kernel<<<NNODES / 4, 256, 0, stream>>>(emb, W, a, tbl, esrc);
    attn_kernel<<<512, 512, 0, stream>>>(adj, tbl, esrc, hout);
    fc_kernel<<<BGRAPH * 100, 256, 0, stream>>>(hout, fc1w, fc1b, out);
}